// Round 1
// baseline (531.370 us; speedup 1.0000x reference)
//
#include <hip/hip_runtime.h>
#include <stdint.h>

#define NROWS 2048
#define NCOLS 50257
#define SCALE 30.0f
// SCALE * log2(e): exp(30*x) == exp2(K2*x)
#define K2 43.28085122666891f

typedef float v4f __attribute__((ext_vector_type(4)));

// v_exp_f32 computes 2^x. Avoid __exp2f (glibc macro collision in this TU).
static __device__ __forceinline__ float fexp2(float x) {
    return __builtin_amdgcn_exp2f(x);
}

// Stage 1: one block per row. Sum exp2(K2*x) over the row, compute the
// per-row loss term L_i, store to partial[row] (no atomics).
__global__ __launch_bounds__(256) void amsoftmax_row_kernel(
    const float* __restrict__ score,
    const int* __restrict__ labels,
    float* __restrict__ partial) {
    const int row = blockIdx.x;
    const int tid = threadIdx.x;
    const float* __restrict__ r = score + (size_t)row * NCOLS;

    const int lab = labels[row];
    const float target = r[lab];
    const float margin = lab ? 0.4f : 0.1f;
    const float num = SCALE * (target - margin);

    // Row base is only 4B-aligned (NCOLS odd). Peel to 16B alignment.
    const uintptr_t addr = (uintptr_t)r;
    const int mis = (int)(((16u - (addr & 15u)) & 15u) >> 2);

    float a0 = 0.0f, a1 = 0.0f, a2 = 0.0f, a3 = 0.0f;
    for (int j = tid; j < mis; j += 256) a0 += fexp2(K2 * r[j]);

    const int nvec = (NCOLS - mis) >> 2;
    const float* __restrict__ rb = r + mis;

    // x4 unroll, 4 independent dwordx4 loads in flight per wave.
    // Plain cached loads: allow L2/L3 retention across iterations.
    int j = tid;
    for (; j + 768 < nvec; j += 1024) {
        v4f v0 = *(const v4f*)(rb + 4 * (size_t)j);
        v4f v1 = *(const v4f*)(rb + 4 * (size_t)(j + 256));
        v4f v2 = *(const v4f*)(rb + 4 * (size_t)(j + 512));
        v4f v3 = *(const v4f*)(rb + 4 * (size_t)(j + 768));
        a0 += fexp2(K2 * v0.x) + fexp2(K2 * v0.y) +
              fexp2(K2 * v0.z) + fexp2(K2 * v0.w);
        a1 += fexp2(K2 * v1.x) + fexp2(K2 * v1.y) +
              fexp2(K2 * v1.z) + fexp2(K2 * v1.w);
        a2 += fexp2(K2 * v2.x) + fexp2(K2 * v2.y) +
              fexp2(K2 * v2.z) + fexp2(K2 * v2.w);
        a3 += fexp2(K2 * v3.x) + fexp2(K2 * v3.y) +
              fexp2(K2 * v3.z) + fexp2(K2 * v3.w);
    }
    for (; j < nvec; j += 256) {
        v4f v = *(const v4f*)(rb + 4 * (size_t)j);
        a0 += fexp2(K2 * v.x) + fexp2(K2 * v.y) +
              fexp2(K2 * v.z) + fexp2(K2 * v.w);
    }
    for (int k = mis + (nvec << 2) + tid; k < NCOLS; k += 256) {
        a1 += fexp2(K2 * r[k]);
    }

    float acc = (a0 + a1) + (a2 + a3);
    for (int off = 32; off > 0; off >>= 1) acc += __shfl_down(acc, off);
    __shared__ float wsum[4];
    if ((tid & 63) == 0) wsum[tid >> 6] = acc;
    __syncthreads();
    if (tid == 0) {
        const float total = wsum[0] + wsum[1] + wsum[2] + wsum[3];
        const float excl = total - fexp2(K2 * target);
        const float denom = __expf(num) + excl;
        const float L = num - __logf(denom);
        partial[row] = L;
    }
}

// Stage 2: one block sums the 2048 per-row losses, writes -mean.
__global__ __launch_bounds__(256) void amsoftmax_reduce_kernel(
    const float* __restrict__ partial,
    float* __restrict__ out) {
    const int tid = threadIdx.x;
    float s = 0.0f;
    #pragma unroll
    for (int i = tid; i < NROWS; i += 256) s += partial[i];
    for (int off = 32; off > 0; off >>= 1) s += __shfl_down(s, off);
    __shared__ float wsum[4];
    if ((tid & 63) == 0) wsum[tid >> 6] = s;
    __syncthreads();
    if (tid == 0) {
        out[0] = -(wsum[0] + wsum[1] + wsum[2] + wsum[3]) *
                 (1.0f / (float)NROWS);
    }
}

extern "C" void kernel_launch(void* const* d_in, const int* in_sizes, int n_in,
                              void* d_out, int out_size, void* d_ws, size_t ws_size,
                              hipStream_t stream) {
    const float* score = (const float*)d_in[0];
    const int* labels = (const int*)d_in[1];
    float* out = (float*)d_out;
    float* partial = (float*)d_ws;  // NROWS floats

    amsoftmax_row_kernel<<<NROWS, 256, 0, stream>>>(score, labels, partial);
    amsoftmax_reduce_kernel<<<1, 256, 0, stream>>>(partial, out);
}